// Round 10
// baseline (138.840 us; speedup 1.0000x reference)
//
#include <hip/hip_runtime.h>

#define GAMMA 0.99f
constexpr int T_DIM = 128;
constexpr int B_DIM = 512;
constexpr int Q_DIM = 50;
constexpr int NROW  = (T_DIM - 1) * B_DIM;   // 65024 loss rows (t<127)
constexpr int SLOT  = 52;                    // LDS ret row stride
constexpr int PACC  = 52;                    // LDS partial row stride
constexpr int R_BLK = 20;                    // ret rows per block
constexpr int KEEP  = -1;
constexpr int GRID_LOSS = (NROW + R_BLK - 1) / R_BLK;   // 3252

// ---------------------------------------------------------------------------
// K1: parallel segmented suffix scan of affine maps, one block per b.
// (unchanged, verified)
// ---------------------------------------------------------------------------
__global__ void __launch_bounds__(128) coeff_kernel(
    const float* __restrict__ reward,
    const int*   __restrict__ step_type,
    const float* __restrict__ discount,
    float* __restrict__ alpha,
    float* __restrict__ beta,
    int*   __restrict__ anchor,
    float* __restrict__ out) {
  __shared__ float sp[128], sqa[128], sqb[128];
  __shared__ int   snv[128];
  const int t = threadIdx.x;
  const int b = blockIdx.x;

  float p, qa, qb; int nv;
  if (t < T_DIM - 1) {
    const bool  last = (step_type[t * B_DIM + b] == 2);
    const float d    = GAMMA * discount[(t + 1) * B_DIM + b];
    const float r    = reward[(t + 1) * B_DIM + b];
    p  = last ? 0.0f : d;
    qa = last ? 1.0f : 0.0f;
    qb = last ? 0.0f : r;
    nv = last ? t    : KEEP;
  } else {
    p = 1.0f; qa = 0.0f; qb = 0.0f; nv = KEEP;
    out[(T_DIM - 1) * B_DIM + b] = 0.0f;
  }
  sp[t] = p; sqa[t] = qa; sqb[t] = qb; snv[t] = nv;
  __syncthreads();

#pragma unroll
  for (int off = 1; off < 128; off <<= 1) {
    const bool act = (t + off) < 128;
    float p2 = 1.0f, qa2 = 0.0f, qb2 = 0.0f; int nv2 = KEEP;
    if (act) { p2 = sp[t+off]; qa2 = sqa[t+off]; qb2 = sqb[t+off]; nv2 = snv[t+off]; }
    __syncthreads();
    if (act) {
      qa = fmaf(p, qa2, qa);
      qb = fmaf(p, qb2, qb);
      p  = p * p2;
      nv = (nv == KEEP) ? nv2 : nv;
      sp[t] = p; sqa[t] = qa; sqb[t] = qb; snv[t] = nv;
    }
    __syncthreads();
  }

  if (t < T_DIM - 1) {
    const int row = (b << 7) + t;
    alpha[row]  = p + qa;
    beta[row]   = qb;
    anchor[row] = (nv == KEEP) ? (T_DIM - 1) : nv;
  }
}

// ---------------------------------------------------------------------------
// K2: quantile huber loss — EXACT R6 structure (best known), with a
// DIAGNOSTIC y-dimension: gridDim.y = 3; y=0 writes real out, y=1,2 redo
// identical work into scratch (same-value benign, no atomics).  This makes
// the loss dispatch ~3x longer so it surfaces in rocprof top-5 with full
// counters, and dur delta vs R6 gives loss duration = delta/2.
// ---------------------------------------------------------------------------
__global__ void __launch_bounds__(256) loss_kernel(
    const float* __restrict__ value,
    const float* __restrict__ tv,
    const float* __restrict__ alpha,
    const float* __restrict__ beta,
    const int*   __restrict__ anchor,
    float*       __restrict__ out_real,
    float*       __restrict__ out_scratch) {
  __shared__ __align__(16) float sret[R_BLK * SLOT];
  __shared__ float pacc[R_BLK * PACC];

  float* __restrict__ out = (blockIdx.y == 0) ? out_real : out_scratch;

  const int tid = threadIdx.x;
  const int r0  = blockIdx.x * R_BLK;

  // ---- stage ret rows r0..r0+19 into LDS (4 passes of 256 threads) ----
  for (int e = tid; e < R_BLK * Q_DIM; e += 256) {
    const int lr  = e / Q_DIM;
    const int i   = e - lr * Q_DIM;
    const int row = r0 + lr;
    float rv = 0.0f;
    if (row < NROW) {
      const int b  = row & (B_DIM - 1);
      const int t  = row >> 9;
      const int ci = (b << 7) + t;
      const int n  = anchor[ci];
      rv = fmaf(alpha[ci], tv[(n * B_DIM + b) * Q_DIM + i], beta[ci]);
    }
    sret[lr * SLOT + i] = rv;
  }
  __syncthreads();

  const bool act   = tid < 5 * Q_DIM;       // 250 active threads
  const int  r_off = tid / Q_DIM;           // 0..4
  const int  j     = tid - r_off * Q_DIM;
  const float tm05 = ((float)j + 0.5f) * (1.0f / Q_DIM) - 0.5f;

  if (act) {
    float vv[4];
#pragma unroll
    for (int rb = 0; rb < 4; ++rb)
      vv[rb] = value[(r0 + rb * 5) * Q_DIM + tid];

#pragma unroll
    for (int rb = 0; rb < 4; ++rb) {
      const int lr = rb * 5 + r_off;
      const float* rp = &sret[lr * SLOT];
      const float v = vv[rb];

      float s1 = 0.0f, s2 = 0.0f;
      auto pair = [&](float reti) {
        const float d = reti - v;
        const float c = __builtin_amdgcn_fmed3f(d, -1.0f, 1.0f);
        const float e = fmaf(-0.5f, c, d);
        s1 = fmaf(e, c, s1);
        s2 = fmaf(e, fabsf(c), s2);
      };
#pragma unroll
      for (int i0 = 0; i0 < 48; i0 += 4) {
        const float4 rr = *reinterpret_cast<const float4*>(rp + i0);
        pair(rr.x); pair(rr.y); pair(rr.z); pair(rr.w);
      }
      {
        const float2 rr = *reinterpret_cast<const float2*>(rp + 48);
        pair(rr.x); pair(rr.y);
      }
      pacc[lr * PACC + j] = fmaf(tm05, s2, 0.5f * s1);
    }
  }
  __syncthreads();

  // ---- per-row reduce: wave w handles rows 5w..5w+4 ----
  const int w    = tid >> 6;
  const int lane = tid & 63;
#pragma unroll
  for (int k = 0; k < 5; ++k) {
    const int lr   = w * 5 + k;
    const int grow = r0 + lr;
    float x = (lane < Q_DIM) ? pacc[lr * PACC + lane] : 0.0f;
#pragma unroll
    for (int off = 32; off > 0; off >>= 1)
      x += __shfl_xor(x, off, 64);
    if (lane == 0 && grow < NROW)
      out[grow] = x * (1.0f / Q_DIM);
  }
}

// ---------------------------------------------------------------------------
extern "C" void kernel_launch(void* const* d_in, const int* in_sizes, int n_in,
                              void* d_out, int out_size, void* d_ws, size_t ws_size,
                              hipStream_t stream) {
  const float* reward       = (const float*)d_in[0];
  const int*   step_type    = (const int*)  d_in[1];
  const float* discount     = (const float*)d_in[2];
  const float* value        = (const float*)d_in[3];
  const float* target_value = (const float*)d_in[4];
  float* out = (float*)d_out;

  float* alpha  = (float*)d_ws;              // [512][128]
  float* beta   = alpha + B_DIM * 128;
  int*   anchor = (int*)(beta + B_DIM * 128);
  float* out_scratch = (float*)((char*)d_ws + (1 << 20));   // 256 KB at +1MB

  coeff_kernel<<<B_DIM, 128, 0, stream>>>(reward, step_type, discount,
                                          alpha, beta, anchor, out);

  loss_kernel<<<dim3(GRID_LOSS, 3), 256, 0, stream>>>(
      value, target_value, alpha, beta, anchor, out, out_scratch);
}

// Round 11
// 101.443 us; speedup vs baseline: 1.3687x; 1.3687x over previous
//
#include <hip/hip_runtime.h>

#define GAMMA 0.99f
constexpr int T_DIM = 128;
constexpr int B_DIM = 512;
constexpr int Q_DIM = 50;
constexpr int TRET  = 127;              // loss rows per b (t = 0..126)
constexpr int SLOT  = 52;               // LDS row stride (208 B, 16B-aligned)
constexpr int NSLOT = TRET * Q_DIM;     // 6350 (row,j) slots per b
constexpr int KEEP  = -1;

// ---------------------------------------------------------------------------
// Fused kernel: one 1024-thread block per b (512 blocks = exactly 2/CU).
// Phase 1: segmented suffix scan of affine maps over t (threads 0..127,
//          Hillis-Steele, 7 rounds) -> alpha/beta/anchor in LDS.
//          ret[t,q] = alpha[t]*tv[anchor[t],b,q] + beta[t].
// Phase 2: stage all 127 ret rows for this b into LDS.
// Phase 3: pair compute, one (t,j) column per slot; 5-op verified math:
//          d = ret_i - v; c = med3(d,-1,1); e = d - 0.5c
//          sum w*h = 0.5*sum(e*c) + (tau_j-0.5)*sum(e*|c|)
// Phase 4: per-row wave reduce -> out[t*B+b].  t=127 zero row written here.
// No workspace, no atomics, single graph node.
// ---------------------------------------------------------------------------
__global__ void __launch_bounds__(1024) fused_kernel(
    const float* __restrict__ reward,
    const int*   __restrict__ step_type,
    const float* __restrict__ discount,
    const float* __restrict__ value,
    const float* __restrict__ tv,
    float*       __restrict__ out) {
  __shared__ __align__(16) float sret[TRET * SLOT];   // 26.4 KB
  __shared__ float pacc[TRET * SLOT];                 // 26.4 KB
  __shared__ float sp[128], sqa[128], sqb[128];
  __shared__ int   snv[128];
  __shared__ float s_alpha[TRET], s_beta[TRET];
  __shared__ int   s_anchor[TRET];

  const int tid = threadIdx.x;
  const int b   = blockIdx.x;

  // ---- phase 1: scan (threads 0..127 active; all threads hit barriers) ----
  float p = 1.0f, qa = 0.0f, qb = 0.0f; int nv = KEEP;
  if (tid < TRET) {
    const bool  last = (step_type[tid * B_DIM + b] == 2);
    const float d    = GAMMA * discount[(tid + 1) * B_DIM + b];
    const float r    = reward[(tid + 1) * B_DIM + b];
    p  = last ? 0.0f : d;
    qa = last ? 1.0f : 0.0f;
    qb = last ? 0.0f : r;
    nv = last ? tid  : KEEP;
  } else if (tid == TRET) {
    out[TRET * B_DIM + b] = 0.0f;       // required zero row (t = 127)
  }
  if (tid < 128) { sp[tid] = p; sqa[tid] = qa; sqb[tid] = qb; snv[tid] = nv; }
  __syncthreads();

#pragma unroll
  for (int off = 1; off < 128; off <<= 1) {
    const bool act = (tid < 128) && (tid + off < 128);
    float p2 = 1.0f, qa2 = 0.0f, qb2 = 0.0f; int nv2 = KEEP;
    if (act) { p2 = sp[tid+off]; qa2 = sqa[tid+off]; qb2 = sqb[tid+off]; nv2 = snv[tid+off]; }
    __syncthreads();
    if (act) {
      qa = fmaf(p, qa2, qa);            // self is the OUTER map
      qb = fmaf(p, qb2, qb);
      p  = p * p2;
      nv = (nv == KEEP) ? nv2 : nv;
      sp[tid] = p; sqa[tid] = qa; sqb[tid] = qb; snv[tid] = nv;
    }
    __syncthreads();
  }

  if (tid < TRET) {
    s_alpha[tid]  = p + qa;             // applied to (a=1, be=0, n=127)
    s_beta[tid]   = qb;
    s_anchor[tid] = (nv == KEEP) ? TRET : nv;
  }
  __syncthreads();

  // ---- phase 2: stage all 127 ret rows for this b ----
  for (int e = tid; e < NSLOT; e += 1024) {
    const int t = e / Q_DIM;
    const int i = e - t * Q_DIM;
    const int n = s_anchor[t];
    sret[t * SLOT + i] =
        fmaf(s_alpha[t], tv[(n * B_DIM + b) * Q_DIM + i], s_beta[t]);
  }
  __syncthreads();

  // ---- phase 3: pair compute ----
  for (int s = tid; s < NSLOT; s += 1024) {
    const int t = s / Q_DIM;
    const int j = s - t * Q_DIM;
    const float v    = value[(t * B_DIM + b) * Q_DIM + j];   // coalesced
    const float tm05 = ((float)j + 0.5f) * (1.0f / Q_DIM) - 0.5f;
    const float* rp  = &sret[t * SLOT];

    float s1 = 0.0f, s2 = 0.0f;
    auto pair = [&](float reti) {
      const float d = reti - v;
      const float c = __builtin_amdgcn_fmed3f(d, -1.0f, 1.0f);
      const float e = fmaf(-0.5f, c, d);
      s1 = fmaf(e, c, s1);              // sum huber(d)
      s2 = fmaf(e, fabsf(c), s2);       // sum sgn(d)*huber(d)
    };
#pragma unroll
    for (int i0 = 0; i0 < 48; i0 += 4) {
      const float4 rr = *reinterpret_cast<const float4*>(rp + i0);
      pair(rr.x); pair(rr.y); pair(rr.z); pair(rr.w);
    }
    {
      const float2 rr = *reinterpret_cast<const float2*>(rp + 48);
      pair(rr.x); pair(rr.y);
    }
    pacc[t * SLOT + j] = fmaf(tm05, s2, 0.5f * s1);
  }
  __syncthreads();

  // ---- phase 4: per-row reduce; wave w handles rows 8w..8w+7 ----
  const int w    = tid >> 6;
  const int lane = tid & 63;
#pragma unroll
  for (int k = 0; k < 8; ++k) {
    const int t = w * 8 + k;
    if (t < TRET) {
      float x = (lane < Q_DIM) ? pacc[t * SLOT + lane] : 0.0f;
#pragma unroll
      for (int off = 32; off > 0; off >>= 1)
        x += __shfl_xor(x, off, 64);
      if (lane == 0) out[t * B_DIM + b] = x * (1.0f / Q_DIM);
    }
  }
}

// ---------------------------------------------------------------------------
extern "C" void kernel_launch(void* const* d_in, const int* in_sizes, int n_in,
                              void* d_out, int out_size, void* d_ws, size_t ws_size,
                              hipStream_t stream) {
  const float* reward       = (const float*)d_in[0];
  const int*   step_type    = (const int*)  d_in[1];
  const float* discount     = (const float*)d_in[2];
  const float* value        = (const float*)d_in[3];
  const float* target_value = (const float*)d_in[4];
  float* out = (float*)d_out;

  fused_kernel<<<B_DIM, 1024, 0, stream>>>(reward, step_type, discount,
                                           value, target_value, out);
}